// Round 1
// baseline (353.143 us; speedup 1.0000x reference)
//
#include <hip/hip_runtime.h>
#include <hip/hip_bf16.h>
#include <cstdint>

#define B_ 64
#define S_ 2048
#define D_ 512
#define H_ 512

typedef short s16x8 __attribute__((ext_vector_type(8)));
typedef float f32x4 __attribute__((ext_vector_type(4)));

static __device__ __forceinline__ unsigned short f2bf(float f) {
  __bf16 h = (__bf16)f;
  return __builtin_bit_cast(unsigned short, h);
}

// ---------------- mask dtype detection ----------------
// mask is bool in the reference; harness may hand us bool-bytes, int32, or
// float32. Scan first 32768 words (valid under all interpretations: bool
// buffer is exactly 32768 words) and classify. Deterministic per-inputs.
__global__ void k_detect(const unsigned int* __restrict__ mw, int* __restrict__ flag) {
  __shared__ int cls;
  if (threadIdx.x == 0) cls = 0;
  __syncthreads();
  int sawFloat = 0, sawGt1 = 0;
  for (int i = threadIdx.x; i < 32768; i += 256) {
    unsigned w = mw[i];
    if (w == 0x3F800000u) sawFloat = 1;
    else if (w > 1u) sawGt1 = 1;
  }
  if (sawFloat) atomicOr(&cls, 2);
  if (sawGt1) atomicOr(&cls, 1);
  __syncthreads();
  if (threadIdx.x == 0) {
    int c = cls;
    *flag = (c & 2) ? 2 : ((c & 1) ? 1 : 0);  // 2=float, 1=bytes, 0=int32
  }
}

// ---------------- W_ctx f32 -> bf16 ----------------
__global__ void k_cvt(const float* __restrict__ W, unsigned short* __restrict__ Wb) {
  int i = (blockIdx.x * 256 + threadIdx.x) * 8;
  float4 a = *(const float4*)(W + i);
  float4 c = *(const float4*)(W + i + 4);
  ushort4 o0 = make_ushort4(f2bf(a.x), f2bf(a.y), f2bf(a.z), f2bf(a.w));
  ushort4 o1 = make_ushort4(f2bf(c.x), f2bf(c.y), f2bf(c.z), f2bf(c.w));
  *(ushort4*)(Wb + i) = o0;
  *(ushort4*)(Wb + i + 4) = o1;
}

// ---------------- inp' = x @ W_in^T + b_in + b_ctx ----------------
__global__ void k_inp(const float* __restrict__ x, const float* __restrict__ W_in,
                      const float* __restrict__ b_in, const float* __restrict__ b_ctx,
                      float* __restrict__ inp_pb) {
  const int b = blockIdx.x, t = threadIdx.x;
  __shared__ float xs[D_];
  xs[t] = x[b * D_ + t];
  xs[t + 256] = x[b * D_ + t + 256];
  __syncthreads();
  for (int h = t; h < H_; h += 256) {
    const float4* wr = (const float4*)(W_in + (size_t)h * D_);
    float acc = 0.f;
#pragma unroll 4
    for (int d4 = 0; d4 < 128; ++d4) {
      float4 w = wr[d4];
      acc += w.x * xs[d4 * 4] + w.y * xs[d4 * 4 + 1] + w.z * xs[d4 * 4 + 2] +
             w.w * xs[d4 * 4 + 3];
    }
    inp_pb[b * H_ + h] = acc + b_in[h] + b_ctx[h];
  }
}

// ---------------- att[b,s] = sum_h V[h]*tanh(inp'[b,h] + (W_ctx@ctx^T)[h,s]) ----
// One WG per (b, 64-wide s-tile). 4 waves, each owns a 128-h slice.
// MFMA 16x16x32 bf16; context tile staged in LDS as bf16, XOR-swizzled.
__global__ __launch_bounds__(256, 2) void k_att(
    const float* __restrict__ context, const unsigned short* __restrict__ Wc,
    const float* __restrict__ inp_pb, const float* __restrict__ V,
    float* __restrict__ att) {
  __shared__ char lds[64 * 128];  // [s][k] bf16, row=128B, swizzled
  __shared__ float red[4][64];
  const int tid = threadIdx.x;
  const int wave = tid >> 6, lane = tid & 63;
  const int b = blockIdx.y, s0 = blockIdx.x * 64;
  const float* ctxb = context + ((size_t)b * S_ + s0) * D_;
  const int hbase = wave * 128;

  f32x4 acc[8][4];
#pragma unroll
  for (int m = 0; m < 8; ++m)
#pragma unroll
    for (int n = 0; n < 4; ++n) acc[m][n] = f32x4{0.f, 0.f, 0.f, 0.f};

  const int col4 = tid & 15, sr0 = tid >> 4;

  for (int kc = 0; kc < D_; kc += 64) {
    __syncthreads();  // protect previous iteration's LDS reads
#pragma unroll
    for (int p = 0; p < 4; ++p) {
      int s = sr0 + p * 16;
      float4 v = *(const float4*)(ctxb + (size_t)s * D_ + kc + col4 * 4);
      ushort4 hb = make_ushort4(f2bf(v.x), f2bf(v.y), f2bf(v.z), f2bf(v.w));
      int byte = (s * 128 + col4 * 8) ^ ((s & 7) << 4);
      *(ushort4*)(lds + byte) = hb;
    }
    __syncthreads();

    s16x8 bfrag[2][4];
#pragma unroll
    for (int kk = 0; kk < 2; ++kk)
#pragma unroll
      for (int n = 0; n < 4; ++n) {
        int s = n * 16 + (lane & 15);
        int byte = (s * 128 + kk * 64 + ((lane >> 4) << 4)) ^ ((s & 7) << 4);
        bfrag[kk][n] = *(const s16x8*)(lds + byte);
      }
#pragma unroll
    for (int kk = 0; kk < 2; ++kk)
#pragma unroll
      for (int m = 0; m < 8; ++m) {
        int h = hbase + m * 16 + (lane & 15);
        int k = kc + kk * 32 + ((lane >> 4) << 3);
        s16x8 afrag = *(const s16x8*)(Wc + (size_t)h * D_ + k);
#pragma unroll
        for (int n = 0; n < 4; ++n)
          acc[m][n] = __builtin_amdgcn_mfma_f32_16x16x32_bf16(afrag, bfrag[kk][n],
                                                              acc[m][n], 0, 0, 0);
      }
  }

  // epilogue: tanh + V-dot, reduce over h
  float attp[4] = {0.f, 0.f, 0.f, 0.f};
  const float* ib = inp_pb + b * H_;
#pragma unroll
  for (int m = 0; m < 8; ++m) {
#pragma unroll
    for (int j = 0; j < 4; ++j) {
      int h = hbase + m * 16 + ((lane >> 4) << 2) + j;
      float c = ib[h];
      float vh = V[h];
#pragma unroll
      for (int n = 0; n < 4; ++n) {
        float x = acc[m][n][j] + c;
        x = fminf(fmaxf(x, -15.f), 15.f);
        float e = __expf(2.f * x);
        attp[n] += vh * __fdividef(e - 1.f, e + 1.f);
      }
    }
  }
#pragma unroll
  for (int n = 0; n < 4; ++n) {
    attp[n] += __shfl_xor(attp[n], 16, 64);
    attp[n] += __shfl_xor(attp[n], 32, 64);
  }
  if (lane < 16) {
#pragma unroll
    for (int n = 0; n < 4; ++n) red[wave][n * 16 + lane] = attp[n];
  }
  __syncthreads();
  if (tid < 64) {
    att[(size_t)b * S_ + s0 + tid] =
        red[0][tid] + red[1][tid] + red[2][tid] + red[3][tid];
  }
}

// ---------------- masked softmax over S -> alpha ----------------
__global__ void k_softmax(const float* __restrict__ att, const void* __restrict__ mask,
                          const int* __restrict__ flag, float* __restrict__ alpha) {
  const int b = blockIdx.x, t = threadIdx.x;
  const int mtype = *flag;
  __shared__ float sm[4];
  const unsigned char* m8 = (const unsigned char*)mask;
  const int* m32 = (const int*)mask;
  const float* mf = (const float*)mask;
  float vals[8];
  float mx = -3.0e38f;
#pragma unroll
  for (int i = 0; i < 8; ++i) {
    int s = t + i * 256;
    size_t idx = (size_t)b * S_ + s;
    int msk = (mtype == 1) ? (int)m8[idx] : (mtype == 2) ? (mf[idx] != 0.f) : m32[idx];
    float v = msk ? -__builtin_inff() : att[idx];
    vals[i] = v;
    mx = fmaxf(mx, v);
  }
  for (int off = 32; off; off >>= 1) mx = fmaxf(mx, __shfl_xor(mx, off, 64));
  if ((t & 63) == 0) sm[t >> 6] = mx;
  __syncthreads();
  mx = fmaxf(fmaxf(sm[0], sm[1]), fmaxf(sm[2], sm[3]));
  float es[8];
  float sum = 0.f;
#pragma unroll
  for (int i = 0; i < 8; ++i) {
    es[i] = __expf(vals[i] - mx);
    sum += es[i];
  }
  for (int off = 32; off; off >>= 1) sum += __shfl_xor(sum, off, 64);
  __syncthreads();
  if ((t & 63) == 0) sm[t >> 6] = sum;
  __syncthreads();
  sum = sm[0] + sm[1] + sm[2] + sm[3];
  float inv = __fdividef(1.f, sum);
#pragma unroll
  for (int i = 0; i < 8; ++i) alpha[(size_t)b * S_ + t + i * 256] = es[i] * inv;
}

// ---------------- y partials: y[b,d] = sum_s alpha*context ----------------
__global__ void k_ypart(const float* __restrict__ context, const float* __restrict__ alpha,
                        float* __restrict__ y_part) {
  const int chunk = blockIdx.x, b = blockIdx.y, t = threadIdx.x;
  __shared__ float al[256];
  __shared__ float4 part[128];
  al[t] = alpha[(size_t)b * S_ + chunk * 256 + t];
  __syncthreads();
  const int d4 = t & 127, sr = t >> 7;
  const float4* base = (const float4*)(context + ((size_t)b * S_ + chunk * 256) * D_);
  float4 acc = make_float4(0.f, 0.f, 0.f, 0.f);
  for (int i = 0; i < 128; ++i) {
    int s = sr + 2 * i;
    float4 v = base[(size_t)s * 128 + d4];
    float a = al[s];
    acc.x += a * v.x; acc.y += a * v.y; acc.z += a * v.z; acc.w += a * v.w;
  }
  if (sr == 1) part[d4] = acc;
  __syncthreads();
  if (sr == 0) {
    float4 o = part[d4];
    o.x += acc.x; o.y += acc.y; o.z += acc.z; o.w += acc.w;
    *(float4*)(y_part + ((size_t)(b * 8 + chunk)) * D_ + d4 * 4) = o;
  }
}

// ---------------- hidden = W_ctx @ y + b_ctx (exact f32) ----------------
__global__ void k_hidden(const float* __restrict__ y_part, const float* __restrict__ W_ctx,
                         const float* __restrict__ b_ctx, float* __restrict__ hidden) {
  const int b = blockIdx.x, t = threadIdx.x;
  __shared__ float ys[D_];
  for (int d = t; d < D_; d += 256) {
    float s = 0.f;
#pragma unroll
    for (int c = 0; c < 8; ++c) s += y_part[((size_t)(b * 8 + c)) * D_ + d];
    ys[d] = s;
  }
  __syncthreads();
  for (int h = t; h < H_; h += 256) {
    const float4* wr = (const float4*)(W_ctx + (size_t)h * D_);
    float acc = 0.f;
#pragma unroll 4
    for (int d4 = 0; d4 < 128; ++d4) {
      float4 w = wr[d4];
      acc += w.x * ys[d4 * 4] + w.y * ys[d4 * 4 + 1] + w.z * ys[d4 * 4 + 2] +
             w.w * ys[d4 * 4 + 3];
    }
    hidden[b * H_ + h] = acc + b_ctx[h];
  }
}

extern "C" void kernel_launch(void* const* d_in, const int* in_sizes, int n_in,
                              void* d_out, int out_size, void* d_ws, size_t ws_size,
                              hipStream_t stream) {
  (void)in_sizes; (void)n_in; (void)out_size; (void)ws_size;
  const float* x = (const float*)d_in[0];
  const float* context = (const float*)d_in[1];
  const void* mask = d_in[2];
  const float* W_in = (const float*)d_in[3];
  const float* b_in = (const float*)d_in[4];
  const float* W_ctx = (const float*)d_in[5];
  const float* b_ctx = (const float*)d_in[6];
  const float* V = (const float*)d_in[7];

  float* out_hidden = (float*)d_out;                 // [B,H]
  float* out_alpha = (float*)d_out + B_ * H_;        // [B,S]

  float* ws_f = (float*)d_ws;
  float* inp_pb = ws_f;                              // B*H
  float* att = inp_pb + B_ * H_;                     // B*S
  float* y_part = att + B_ * S_;                     // B*8*D
  int* flag = (int*)(y_part + B_ * 8 * D_);          // 16 ints
  unsigned short* Wb = (unsigned short*)(flag + 16); // H*D bf16

  k_detect<<<1, 256, 0, stream>>>((const unsigned int*)mask, flag);
  k_cvt<<<(H_ * D_) / (256 * 8), 256, 0, stream>>>(W_ctx, Wb);
  k_inp<<<B_, 256, 0, stream>>>(x, W_in, b_in, b_ctx, inp_pb);
  k_att<<<dim3(S_ / 64, B_), 256, 0, stream>>>(context, Wb, inp_pb, V, att);
  k_softmax<<<B_, 256, 0, stream>>>(att, mask, flag, out_alpha);
  k_ypart<<<dim3(8, B_), 256, 0, stream>>>(context, out_alpha, y_part);
  k_hidden<<<B_, 256, 0, stream>>>(y_part, W_ctx, b_ctx, out_hidden);
}

// Round 2
// 315.225 us; speedup vs baseline: 1.1203x; 1.1203x over previous
//
#include <hip/hip_runtime.h>
#include <hip/hip_bf16.h>
#include <cstdint>

#define B_ 64
#define S_ 2048
#define D_ 512
#define H_ 512

typedef short s16x8 __attribute__((ext_vector_type(8)));
typedef float f32x4 __attribute__((ext_vector_type(4)));

static __device__ __forceinline__ unsigned short f2bf(float f) {
  __bf16 h = (__bf16)f;
  return __builtin_bit_cast(unsigned short, h);
}

// ---------------- mask dtype detection (parallel) ----------------
// mask is bool in the reference; harness may hand us bool-bytes, int32, or
// float32. Scan 32768 words (valid under all interpretations) and classify
// into bit flags: bit1 = saw float 1.0f pattern, bit0 = saw word > 1.
__global__ void k_zero(int* __restrict__ flag) {
  if (threadIdx.x == 0) *flag = 0;
}
__global__ void k_detect(const unsigned int* __restrict__ mw, int* __restrict__ flag) {
  int i = blockIdx.x * 256 + threadIdx.x;  // 128 blocks x 256 = 32768
  unsigned w = mw[i];
  int bits = 0;
  if (w == 0x3F800000u) bits = 2;
  else if (w > 1u) bits = 1;
  unsigned long long a1 = __ballot(bits & 1);
  unsigned long long a2 = __ballot(bits & 2);
  if ((threadIdx.x & 63) == 0) {
    int v = (a1 ? 1 : 0) | (a2 ? 2 : 0);
    if (v) atomicOr(flag, v);
  }
}

// ---------------- W_ctx f32 -> bf16 ----------------
__global__ void k_cvt(const float* __restrict__ W, unsigned short* __restrict__ Wb) {
  int i = (blockIdx.x * 256 + threadIdx.x) * 8;
  float4 a = *(const float4*)(W + i);
  float4 c = *(const float4*)(W + i + 4);
  ushort4 o0 = make_ushort4(f2bf(a.x), f2bf(a.y), f2bf(a.z), f2bf(a.w));
  ushort4 o1 = make_ushort4(f2bf(c.x), f2bf(c.y), f2bf(c.z), f2bf(c.w));
  *(ushort4*)(Wb + i) = o0;
  *(ushort4*)(Wb + i + 4) = o1;
}

// ---------------- inp' = x @ W_in^T + b_in + b_ctx ----------------
__global__ void k_inp(const float* __restrict__ x, const float* __restrict__ W_in,
                      const float* __restrict__ b_in, const float* __restrict__ b_ctx,
                      float* __restrict__ inp_pb) {
  const int b = blockIdx.x, t = threadIdx.x;
  __shared__ float xs[D_];
  xs[t] = x[b * D_ + t];
  xs[t + 256] = x[b * D_ + t + 256];
  __syncthreads();
  for (int h = t; h < H_; h += 256) {
    const float4* wr = (const float4*)(W_in + (size_t)h * D_);
    float acc = 0.f;
#pragma unroll 4
    for (int d4 = 0; d4 < 128; ++d4) {
      float4 w = wr[d4];
      acc += w.x * xs[d4 * 4] + w.y * xs[d4 * 4 + 1] + w.z * xs[d4 * 4 + 2] +
             w.w * xs[d4 * 4 + 3];
    }
    inp_pb[b * H_ + h] = acc + b_in[h] + b_ctx[h];
  }
}

// ---------------- att[b,s] = sum_h V[h]*tanh(inp'[b,h] + (W_ctx@ctx^T)[h,s]) ----
// One WG per (b, 64-wide s-tile). 4 waves, each owns a 128-h slice.
// MFMA 16x16x32 bf16. Double-buffered LDS (bf16, XOR-swizzled); next tile's
// global loads issued before current tile's MFMAs (T14 issue-early/write-late).
__global__ __launch_bounds__(256, 2) void k_att(
    const float* __restrict__ context, const unsigned short* __restrict__ Wc,
    const float* __restrict__ inp_pb, const float* __restrict__ V,
    float* __restrict__ att) {
  __shared__ char lds[2][8192];  // [buf][s][k] bf16, row=128B, swizzled
  __shared__ float red[4][64];
  const int tid = threadIdx.x;
  const int wave = tid >> 6, lane = tid & 63;
  const int b = blockIdx.y, s0 = blockIdx.x * 64;
  const float* ctxb = context + ((size_t)b * S_ + s0) * D_;
  const int hbase = wave * 128;
  const int col4 = tid & 15, sr0 = tid >> 4;

  f32x4 acc[8][4];
#pragma unroll
  for (int m = 0; m < 8; ++m)
#pragma unroll
    for (int n = 0; n < 4; ++n) acc[m][n] = f32x4{0.f, 0.f, 0.f, 0.f};

  float4 stg[4];
  auto load_tile = [&](int kc) {
#pragma unroll
    for (int p = 0; p < 4; ++p)
      stg[p] = *(const float4*)(ctxb + (size_t)(sr0 + p * 16) * D_ + kc + col4 * 4);
  };
  auto write_tile = [&](int buf) {
#pragma unroll
    for (int p = 0; p < 4; ++p) {
      int s = sr0 + p * 16;
      ushort4 hb = make_ushort4(f2bf(stg[p].x), f2bf(stg[p].y), f2bf(stg[p].z),
                                f2bf(stg[p].w));
      int byte = (s * 128 + col4 * 8) ^ ((s & 7) << 4);
      *(ushort4*)(&lds[buf][byte]) = hb;
    }
  };

  // prologue: tile 0
  load_tile(0);
  write_tile(0);
  __syncthreads();

  for (int t = 0; t < 8; ++t) {
    const int cur = t & 1;
    if (t < 7) load_tile((t + 1) * 64);  // issue early; consumed after MFMAs

    s16x8 bfrag[2][4];
#pragma unroll
    for (int kk = 0; kk < 2; ++kk)
#pragma unroll
      for (int n = 0; n < 4; ++n) {
        int s = n * 16 + (lane & 15);
        int byte = (s * 128 + kk * 64 + ((lane >> 4) << 4)) ^ ((s & 7) << 4);
        bfrag[kk][n] = *(const s16x8*)(&lds[cur][byte]);
      }
    const int kc0 = t * 64;
#pragma unroll
    for (int kk = 0; kk < 2; ++kk)
#pragma unroll
      for (int m = 0; m < 8; ++m) {
        int h = hbase + m * 16 + (lane & 15);
        int k = kc0 + kk * 32 + ((lane >> 4) << 3);
        s16x8 afrag = *(const s16x8*)(Wc + (size_t)h * D_ + k);
#pragma unroll
        for (int n = 0; n < 4; ++n)
          acc[m][n] = __builtin_amdgcn_mfma_f32_16x16x32_bf16(afrag, bfrag[kk][n],
                                                              acc[m][n], 0, 0, 0);
      }
    if (t < 7) write_tile(cur ^ 1);  // write late, other buffer (safe: its last
                                     // readers synced at end of iter t-1)
    __syncthreads();
  }

  // epilogue: tanh + V-dot, reduce over h
  float attp[4] = {0.f, 0.f, 0.f, 0.f};
  const float* ib = inp_pb + b * H_;
#pragma unroll
  for (int m = 0; m < 8; ++m) {
#pragma unroll
    for (int j = 0; j < 4; ++j) {
      int h = hbase + m * 16 + ((lane >> 4) << 2) + j;
      float c = ib[h];
      float vh = V[h];
#pragma unroll
      for (int n = 0; n < 4; ++n) {
        float x = acc[m][n][j] + c;
        x = fminf(fmaxf(x, -15.f), 15.f);
        float e = __expf(2.f * x);
        attp[n] += vh * __fdividef(e - 1.f, e + 1.f);
      }
    }
  }
#pragma unroll
  for (int n = 0; n < 4; ++n) {
    attp[n] += __shfl_xor(attp[n], 16, 64);
    attp[n] += __shfl_xor(attp[n], 32, 64);
  }
  if (lane < 16) {
#pragma unroll
    for (int n = 0; n < 4; ++n) red[wave][n * 16 + lane] = attp[n];
  }
  __syncthreads();
  if (tid < 64) {
    att[(size_t)b * S_ + s0 + tid] =
        red[0][tid] + red[1][tid] + red[2][tid] + red[3][tid];
  }
}

// ---------------- masked softmax over S -> alpha ----------------
__global__ void k_softmax(const float* __restrict__ att, const void* __restrict__ mask,
                          const int* __restrict__ flag, float* __restrict__ alpha) {
  const int b = blockIdx.x, t = threadIdx.x;
  const int c = *flag;
  const int mtype = (c & 2) ? 2 : (c & 1);  // 2=float, 1=bytes, 0=int32
  __shared__ float sm[4];
  const unsigned char* m8 = (const unsigned char*)mask;
  const int* m32 = (const int*)mask;
  const float* mf = (const float*)mask;
  float vals[8];
  float mx = -3.0e38f;
#pragma unroll
  for (int i = 0; i < 8; ++i) {
    int s = t + i * 256;
    size_t idx = (size_t)b * S_ + s;
    int msk = (mtype == 1) ? (int)m8[idx] : (mtype == 2) ? (mf[idx] != 0.f) : m32[idx];
    float v = msk ? -__builtin_inff() : att[idx];
    vals[i] = v;
    mx = fmaxf(mx, v);
  }
  for (int off = 32; off; off >>= 1) mx = fmaxf(mx, __shfl_xor(mx, off, 64));
  if ((t & 63) == 0) sm[t >> 6] = mx;
  __syncthreads();
  mx = fmaxf(fmaxf(sm[0], sm[1]), fmaxf(sm[2], sm[3]));
  float es[8];
  float sum = 0.f;
#pragma unroll
  for (int i = 0; i < 8; ++i) {
    es[i] = __expf(vals[i] - mx);
    sum += es[i];
  }
  for (int off = 32; off; off >>= 1) sum += __shfl_xor(sum, off, 64);
  __syncthreads();
  if ((t & 63) == 0) sm[t >> 6] = sum;
  __syncthreads();
  sum = sm[0] + sm[1] + sm[2] + sm[3];
  float inv = __fdividef(1.f, sum);
#pragma unroll
  for (int i = 0; i < 8; ++i) alpha[(size_t)b * S_ + t + i * 256] = es[i] * inv;
}

// ---------------- y partials: y[b,d] = sum_s alpha*context ----------------
__global__ void k_ypart(const float* __restrict__ context, const float* __restrict__ alpha,
                        float* __restrict__ y_part) {
  const int chunk = blockIdx.x, b = blockIdx.y, t = threadIdx.x;
  __shared__ float al[256];
  __shared__ float4 part[128];
  al[t] = alpha[(size_t)b * S_ + chunk * 256 + t];
  __syncthreads();
  const int d4 = t & 127, sr = t >> 7;
  const float4* base = (const float4*)(context + ((size_t)b * S_ + chunk * 256) * D_);
  float4 acc = make_float4(0.f, 0.f, 0.f, 0.f);
  for (int i = 0; i < 128; ++i) {
    int s = sr + 2 * i;
    float4 v = base[(size_t)s * 128 + d4];
    float a = al[s];
    acc.x += a * v.x; acc.y += a * v.y; acc.z += a * v.z; acc.w += a * v.w;
  }
  if (sr == 1) part[d4] = acc;
  __syncthreads();
  if (sr == 0) {
    float4 o = part[d4];
    o.x += acc.x; o.y += acc.y; o.z += acc.z; o.w += acc.w;
    *(float4*)(y_part + ((size_t)(b * 8 + chunk)) * D_ + d4 * 4) = o;
  }
}

// ---------------- hidden = W_ctx @ y + b_ctx (exact f32) ----------------
__global__ void k_hidden(const float* __restrict__ y_part, const float* __restrict__ W_ctx,
                         const float* __restrict__ b_ctx, float* __restrict__ hidden) {
  const int b = blockIdx.x, t = threadIdx.x;
  __shared__ float ys[D_];
  for (int d = t; d < D_; d += 256) {
    float s = 0.f;
#pragma unroll
    for (int c = 0; c < 8; ++c) s += y_part[((size_t)(b * 8 + c)) * D_ + d];
    ys[d] = s;
  }
  __syncthreads();
  for (int h = t; h < H_; h += 256) {
    const float4* wr = (const float4*)(W_ctx + (size_t)h * D_);
    float acc = 0.f;
#pragma unroll 4
    for (int d4 = 0; d4 < 128; ++d4) {
      float4 w = wr[d4];
      acc += w.x * ys[d4 * 4] + w.y * ys[d4 * 4 + 1] + w.z * ys[d4 * 4 + 2] +
             w.w * ys[d4 * 4 + 3];
    }
    hidden[b * H_ + h] = acc + b_ctx[h];
  }
}

extern "C" void kernel_launch(void* const* d_in, const int* in_sizes, int n_in,
                              void* d_out, int out_size, void* d_ws, size_t ws_size,
                              hipStream_t stream) {
  (void)in_sizes; (void)n_in; (void)out_size; (void)ws_size;
  const float* x = (const float*)d_in[0];
  const float* context = (const float*)d_in[1];
  const void* mask = d_in[2];
  const float* W_in = (const float*)d_in[3];
  const float* b_in = (const float*)d_in[4];
  const float* W_ctx = (const float*)d_in[5];
  const float* b_ctx = (const float*)d_in[6];
  const float* V = (const float*)d_in[7];

  float* out_hidden = (float*)d_out;                 // [B,H]
  float* out_alpha = (float*)d_out + B_ * H_;        // [B,S]

  float* ws_f = (float*)d_ws;
  float* inp_pb = ws_f;                              // B*H
  float* att = inp_pb + B_ * H_;                     // B*S
  float* y_part = att + B_ * S_;                     // B*8*D
  int* flag = (int*)(y_part + B_ * 8 * D_);          // 16 ints
  unsigned short* Wb = (unsigned short*)(flag + 16); // H*D bf16

  k_zero<<<1, 64, 0, stream>>>(flag);
  k_detect<<<128, 256, 0, stream>>>((const unsigned int*)mask, flag);
  k_cvt<<<(H_ * D_) / (256 * 8), 256, 0, stream>>>(W_ctx, Wb);
  k_inp<<<B_, 256, 0, stream>>>(x, W_in, b_in, b_ctx, inp_pb);
  k_att<<<dim3(S_ / 64, B_), 256, 0, stream>>>(context, Wb, inp_pb, V, att);
  k_softmax<<<B_, 256, 0, stream>>>(att, mask, flag, out_alpha);
  k_ypart<<<dim3(8, B_), 256, 0, stream>>>(context, out_alpha, y_part);
  k_hidden<<<B_, 256, 0, stream>>>(y_part, W_ctx, b_ctx, out_hidden);
}